// Round 10
// baseline (937.784 us; speedup 1.0000x reference)
//
#include <hip/hip_runtime.h>

#define BATCH 16
#define TXT   320
#define NMELC 80
#define MELT  2000
#define NW    504          // coefficient windows allocated per batch
#define PADM  1.0e12f
#define INF9  1.0e9f
#define EPSC  1e-7f
#define L2E   1.4426950408889634f
#define LN2   0.6931471805599453f
#define EPSL2 1.4426950e-7f

// ---------------------------------------------------------------------------
// Kernel A: log_prob (unchanged r9 structure).
// ---------------------------------------------------------------------------
__global__ __launch_bounds__(256) void lp_kernel(
    const float* __restrict__ mlv,   // (B,320,160)
    const float* __restrict__ ms,    // (B,80,2000)
    float* __restrict__ out_lp)      // (B,320,2000)  (d_out+1)
{
    __shared__ float Gt[16][64];
    __shared__ float Ft[16][256];
    __shared__ float bias_s[64];
    __shared__ float bias_p[256];

    const int b   = blockIdx.z;
    const int j0  = blockIdx.y * 64;
    const int t0  = blockIdx.x * 256;
    const int tid = threadIdx.x;
    const float s = -0.00625f;  // -0.5/80

    const float* mlv_b = mlv + (size_t)b * TXT * 160;
    const float* ms_b  = ms  + (size_t)b * NMELC * MELT;

    {
        const int jj = tid >> 2;
        const int q  = tid & 3;
        const float* p = mlv_b + (size_t)(j0 + jj) * 160 + q * 20;
        float part = 0.f;
        #pragma unroll
        for (int c = 0; c < 20; ++c) {
            float mu = p[c];
            float lv = p[c + 80];
            float iv = __expf(-lv);
            part += mu * mu * iv + lv;
        }
        bias_p[tid] = part;
    }
    __syncthreads();
    if (tid < 64) {
        float v = bias_p[tid * 4] + bias_p[tid * 4 + 1] +
                  bias_p[tid * 4 + 2] + bias_p[tid * 4 + 3];
        bias_s[tid] = s * v;
    }

    float acc[8][8];
    #pragma unroll
    for (int i = 0; i < 8; ++i)
        #pragma unroll
        for (int k = 0; k < 8; ++k) acc[i][k] = 0.f;

    const int jg = tid >> 5;   // 0..7
    const int tg = tid & 31;   // 0..31

    for (int kc = 0; kc < 10; ++kc) {
        const int c0 = kc * 8;
        __syncthreads();
        #pragma unroll
        for (int i = 0; i < 2; ++i) {
            int f   = tid + i * 256;
            int cr  = f >> 6;
            int col = f & 63;
            float mu = mlv_b[(size_t)(j0 + col) * 160 + (c0 + cr)];
            float lv = mlv_b[(size_t)(j0 + col) * 160 + (80 + c0 + cr)];
            float iv = __expf(-lv);
            Gt[cr][col]     = s * iv;
            Gt[cr + 8][col] = -2.f * s * mu * iv;
        }
        #pragma unroll
        for (int i = 0; i < 2; ++i) {
            int f   = tid + i * 256;
            int row = f >> 6;
            int c4  = f & 63;
            int t   = t0 + c4 * 4;
            float4 v = (t + 3 < MELT)
                ? *(const float4*)&ms_b[(size_t)(c0 + row) * MELT + t]
                : make_float4(0.f, 0.f, 0.f, 0.f);
            *(float4*)&Ft[row][c4 * 4] =
                make_float4(v.x * v.x, v.y * v.y, v.z * v.z, v.w * v.w);
            *(float4*)&Ft[row + 8][c4 * 4] = v;
        }
        __syncthreads();
        #pragma unroll
        for (int k = 0; k < 16; ++k) {
            float4 g0 = *(const float4*)&Gt[k][jg * 8];
            float4 g1 = *(const float4*)&Gt[k][jg * 8 + 4];
            float4 f0 = *(const float4*)&Ft[k][tg * 8];
            float4 f1 = *(const float4*)&Ft[k][tg * 8 + 4];
            float ga[8] = {g0.x, g0.y, g0.z, g0.w, g1.x, g1.y, g1.z, g1.w};
            float fa[8] = {f0.x, f0.y, f0.z, f0.w, f1.x, f1.y, f1.z, f1.w};
            #pragma unroll
            for (int ji = 0; ji < 8; ++ji)
                #pragma unroll
                for (int ti = 0; ti < 8; ++ti)
                    acc[ji][ti] = fmaf(ga[ji], fa[ti], acc[ji][ti]);
        }
    }

    #pragma unroll
    for (int ji = 0; ji < 8; ++ji) {
        int j = j0 + jg * 8 + ji;
        float bs = bias_s[jg * 8 + ji];
        float* orow = out_lp + (size_t)(b * TXT + j) * MELT;
        #pragma unroll
        for (int ti = 0; ti < 8; ++ti) {
            int t = t0 + tg * 8 + ti;
            if (t < MELT) orow[t] = acc[ji][ti] + bs;
        }
    }
}

// ---------------------------------------------------------------------------
// log2-domain pairwise lse (exact; exp2 underflows to 0 for -INF9 inputs)
// ---------------------------------------------------------------------------
__device__ __forceinline__ float lse2l(float x, float y) {
    float m = fmaxf(x, y);
    float d = x - y;
    float e = __builtin_amdgcn_exp2f(-fabsf(d));
    return m + __builtin_amdgcn_logf(1.0f + e);
}

// ---------------------------------------------------------------------------
// Kernel A2: K=4 composed-operator coefficients.
// Window W covers steps t = 4W+1..4W+4 (steps with t > tend are identity).
// C_k[j] (k=0..4): a_{4(W+1)}[j] = lse_k( a_{4W}[j-k] + C_k[j] ).
// Built by composing per-step band ops; p = lp*L2E + EPS*L2E (log2 domain).
// Block = (Wg, b): stages lp slice [320][64] in LDS (coalesced), 16 windows.
// Output layout: C[b][W][k][j] — coalesced j-writes.
// ---------------------------------------------------------------------------
__global__ __launch_bounds__(320) void coeff_kernel(
    const float* __restrict__ lp,    // (B,320,2000) = out_lp
    const int* __restrict__ mlen,
    float* __restrict__ Cc)          // (B,NW,5,320)
{
    __shared__ float sl[320][65];

    const int Wg  = blockIdx.x;      // 0..31
    const int b   = blockIdx.y;
    const int tid = threadIdx.x;
    const int tend = mlen[b] - 1;

    // stage slice: sl[j][s] = p(t = 64Wg + 1 + s), coalesced along t
    {
        const int g  = tid >> 6;
        const int tl_ = tid & 63;
        const int t  = 64 * Wg + 1 + tl_;
        for (int r = 0; r < 64; ++r) {
            int j = g * 64 + r;
            float v = (t < MELT) ? lp[((size_t)b * TXT + j) * MELT + t] : 0.f;
            sl[j][tl_] = fmaf(v, L2E, EPSL2);
        }
    }
    __syncthreads();

    const int j = tid;
    const int j1 = j >= 1 ? j - 1 : 0;
    const int j2 = j >= 2 ? j - 2 : 0;
    const int j3 = j >= 3 ? j - 3 : 0;

    for (int wi = 0; wi < 16; ++wi) {
        const int W = Wg * 16 + wi;
        if (W >= NW) break;
        const int col = 4 * wi;

        // B_d = composed coeffs at target column j-d; identity init
        float B0[5] = {0.f, -INF9, -INF9, -INF9, -INF9};
        float B1[5] = {0.f, -INF9, -INF9, -INF9, -INF9};
        float B2[5] = {0.f, -INF9, -INF9, -INF9, -INF9};
        float B3[5] = {0.f, -INF9, -INF9, -INF9, -INF9};

        // step 1 (t = 4W+1): update d=0..3, bands r=0..1
        if (4 * W + 1 <= tend) {
            float p0 = sl[j][col], p1 = sl[j1][col], p2 = sl[j2][col], p3 = sl[j3][col];
            // B4 = identity: B4[0]=0, else -INF9
            B3[1] = p3 + lse2l(B3[1], 0.f);      B3[0] = p3 + B3[0];
            B2[1] = p2 + lse2l(B2[1], B3[0] - p3); // careful: need OLD B3
            // -- rewrite with explicit olds to avoid ordering bugs:
        }
        // The above ordering is error-prone; redo cleanly with old-copies:
        {
            float O0[5], O1[5], O2[5], O3[5];
            #pragma unroll
            for (int r = 0; r < 5; ++r) { O0[r]=0.f; O1[r]=0.f; O2[r]=0.f; O3[r]=0.f; }
            // re-init (identity)
            #pragma unroll
            for (int r = 0; r < 5; ++r) {
                B0[r] = r==0?0.f:-INF9; B1[r] = r==0?0.f:-INF9;
                B2[r] = r==0?0.f:-INF9; B3[r] = r==0?0.f:-INF9;
            }
            // step 1: d=0..3 (B4_old = identity)
            if (4 * W + 1 <= tend) {
                float p0 = sl[j][col], p1 = sl[j1][col], p2 = sl[j2][col], p3 = sl[j3][col];
                #pragma unroll
                for (int r = 0; r < 5; ++r) { O0[r]=B0[r]; O1[r]=B1[r]; O2[r]=B2[r]; O3[r]=B3[r]; }
                B0[0] = p0 + O0[0];  B0[1] = p0 + lse2l(O0[1], O1[0]);
                B1[0] = p1 + O1[0];  B1[1] = p1 + lse2l(O1[1], O2[0]);
                B2[0] = p2 + O2[0];  B2[1] = p2 + lse2l(O2[1], O3[0]);
                B3[0] = p3 + O3[0];  B3[1] = p3 + lse2l(O3[1], 0.f);   // B4_old[0]=0
            }
            // step 2: d=0..2, r=0..2
            if (4 * W + 2 <= tend) {
                float p0 = sl[j][col+1], p1 = sl[j1][col+1], p2 = sl[j2][col+1];
                #pragma unroll
                for (int r = 0; r < 5; ++r) { O0[r]=B0[r]; O1[r]=B1[r]; O2[r]=B2[r]; O3[r]=B3[r]; }
                B0[0] = p0 + O0[0];
                B0[1] = p0 + lse2l(O0[1], O1[0]);
                B0[2] = p0 + lse2l(O0[2], O1[1]);
                B1[0] = p1 + O1[0];
                B1[1] = p1 + lse2l(O1[1], O2[0]);
                B1[2] = p1 + lse2l(O1[2], O2[1]);
                B2[0] = p2 + O2[0];
                B2[1] = p2 + lse2l(O2[1], O3[0]);
                B2[2] = p2 + lse2l(O2[2], O3[1]);
            }
            // step 3: d=0..1, r=0..3
            if (4 * W + 3 <= tend) {
                float p0 = sl[j][col+2], p1 = sl[j1][col+2];
                #pragma unroll
                for (int r = 0; r < 5; ++r) { O0[r]=B0[r]; O1[r]=B1[r]; O2[r]=B2[r]; }
                B0[0] = p0 + O0[0];
                B0[1] = p0 + lse2l(O0[1], O1[0]);
                B0[2] = p0 + lse2l(O0[2], O1[1]);
                B0[3] = p0 + lse2l(O0[3], O1[2]);
                B1[0] = p1 + O1[0];
                B1[1] = p1 + lse2l(O1[1], O2[0]);
                B1[2] = p1 + lse2l(O1[2], O2[1]);
                B1[3] = p1 + lse2l(O1[3], O2[2]);
            }
            // step 4: d=0, r=0..4
            if (4 * W + 4 <= tend) {
                float p0 = sl[j][col+3];
                #pragma unroll
                for (int r = 0; r < 5; ++r) { O0[r]=B0[r]; O1[r]=B1[r]; }
                B0[0] = p0 + O0[0];
                B0[1] = p0 + lse2l(O0[1], O1[0]);
                B0[2] = p0 + lse2l(O0[2], O1[1]);
                B0[3] = p0 + lse2l(O0[3], O1[2]);
                B0[4] = p0 + lse2l(O0[4], O1[3]);
            }
        }
        // left-edge mask: paths off j<0 don't exist
        if (j < 1) B0[1] = -INF9;
        if (j < 2) B0[2] = -INF9;
        if (j < 3) B0[3] = -INF9;
        if (j < 4) B0[4] = -INF9;

        float* cp = Cc + (((size_t)b * NW + W) * 5) * 320 + j;
        cp[0]    = B0[0];
        cp[320]  = B0[1];
        cp[640]  = B0[2];
        cp[960]  = B0[3];
        cp[1280] = B0[4];
    }
}

// ---------------------------------------------------------------------------
// Kernel B: forward DP v9 — K=4 composed operator. 1 j/lane, 5 waves,
// systolic skew: lane l computes window W = i - l (4 t-steps per iteration).
// Neighbors a[j-1..j-4] via 4-deep DPP wave_shr history; wave boundary via
// per-window LDS ring (4 floats). Windows clamped to [0, Wmax-1]; pre-start
// absorbed by -PADM; post-end latched (aF).
// ---------------------------------------------------------------------------
__device__ __forceinline__ float dpp_shr1(float x) {
    return __int_as_float(__builtin_amdgcn_update_dpp(
        0, __float_as_int(x), 0x138 /*wave_shr:1*/, 0xF, 0xF, false));
}

__global__ __launch_bounds__(320, 1) void dp_kernel(
    const float* __restrict__ Cc,    // (B,NW,5,320)
    const float* __restrict__ lp,    // out_lp (for lp[b,0,0])
    const int* __restrict__ tlen,
    const int* __restrict__ mlen,
    float* __restrict__ res,
    float* __restrict__ out0)
{
    __shared__ float bnd[4][NW][4];
    __shared__ int   prog[4];

    const int b    = blockIdx.x;
    const int tid  = threadIdx.x;
    const int w    = tid >> 6;
    const int l    = tid & 63;
    const int j    = tid;
    const int tend = mlen[b] - 1;
    const int tl   = tlen[b];
    const int Wmax = (tend + 3) >> 2;           // ceil(tend/4), <= 500

    if (tid < 4) prog[tid] = 0;

    float a  = (j == 0) ? lp[(size_t)b * TXT * MELT] * L2E : -PADM;
    float aF = a;
    if (l >= 60 && w < 4) bnd[w][0][l - 60] = a;   // ring[0] = initial state
    __syncthreads();

    float H1 = -PADM, H2 = -PADM, H3 = -PADM, H4 = -PADM;
    const bool hasRing = (w > 0);
    int seen = -1;
    const float* Cb = Cc + ((size_t)b * NW * 5) * 320 + j;
    const int imax = Wmax - 1 + 63;

    float CA[4][5], CB[4][5];
    float RA[4][4], RB[4][4];
    #pragma unroll
    for (int q = 0; q < 4; ++q)
        #pragma unroll
        for (int k = 0; k < 4; ++k) { RA[q][k] = -PADM; RB[q][k] = -PADM; }

#define CLAMPW(I_, OUT_) { int W_ = (I_) - l; W_ = W_ < 0 ? 0 : W_;          \
    OUT_ = W_ > Wmax - 1 ? Wmax - 1 : W_; }

#define POLLTO(TGT_) if (hasRing) {                                          \
    int need_ = (TGT_); if (need_ > Wmax - 1) need_ = Wmax - 1;              \
    if (seen < need_) {                                                      \
        int t2_ = need_ + 16; if (t2_ > Wmax - 1) t2_ = Wmax - 1;            \
        volatile int* pv_ = &prog[w - 1];                                    \
        int v_ = *pv_;                                                       \
        while (v_ < t2_) { __builtin_amdgcn_s_sleep(1); v_ = *pv_; }         \
        seen = v_;                                                           \
        __asm__ volatile("" ::: "memory");                                   \
    } }

#define LOADG(CX_, RX_, IB_) {                                               \
    _Pragma("unroll")                                                        \
    for (int q_ = 0; q_ < 4; ++q_) {                                         \
        int We_; CLAMPW((IB_) + q_, We_)                                     \
        const float* cp_ = Cb + (size_t)We_ * 1600;                          \
        CX_[q_][0] = cp_[0];    CX_[q_][1] = cp_[320];                       \
        CX_[q_][2] = cp_[640];  CX_[q_][3] = cp_[960];                       \
        CX_[q_][4] = cp_[1280];                                              \
        if (hasRing) {                                                       \
            if (l < 1) RX_[q_][0] = bnd[w - 1][We_][3];                      \
            if (l < 2) RX_[q_][1] = bnd[w - 1][We_][l + 2];                  \
            if (l < 3) RX_[q_][2] = bnd[w - 1][We_][l + 1];                  \
            if (l < 4) RX_[q_][3] = bnd[w - 1][We_][l];                      \
        }                                                                    \
    } }

#define STEP(CQ_, RQ_, I_) {                                                 \
    H4 = dpp_shr1(H3); H3 = dpp_shr1(H2); H2 = dpp_shr1(H1);                 \
    H1 = dpp_shr1(a);                                                        \
    float N1_ = (l >= 1) ? H1 : RQ_[0];                                      \
    float N2_ = (l >= 2) ? H2 : RQ_[1];                                      \
    float N3_ = (l >= 3) ? H3 : RQ_[2];                                      \
    float N4_ = (l >= 4) ? H4 : RQ_[3];                                      \
    float x0_ = a   + CQ_[0];                                                \
    float x1_ = N1_ + CQ_[1];                                                \
    float x2_ = N2_ + CQ_[2];                                                \
    float x3_ = N3_ + CQ_[3];                                                \
    float x4_ = N4_ + CQ_[4];                                                \
    float m_ = fmaxf(fmaxf(fmaxf(x0_, x1_), fmaxf(x2_, x3_)), x4_);          \
    float s_ = __builtin_amdgcn_exp2f(x0_ - m_)                              \
             + __builtin_amdgcn_exp2f(x1_ - m_)                              \
             + __builtin_amdgcn_exp2f(x2_ - m_)                              \
             + __builtin_amdgcn_exp2f(x3_ - m_)                              \
             + __builtin_amdgcn_exp2f(x4_ - m_);                             \
    a = m_ + __builtin_amdgcn_logf(s_);                                      \
    aF = ((I_) - l == Wmax - 1) ? a : aF;                                    \
    if (l >= 60 && w < 4) {                                                  \
        int Wp_ = (I_) - l + 1;                                              \
        if (Wp_ >= 1 && Wp_ <= Wmax - 1) bnd[w][Wp_][l - 60] = a;            \
    } }

#define PHASE(CC_, RC_, CN_, RN_, I0_) {                                     \
    POLLTO((I0_) + 7)                                                        \
    LOADG(CN_, RN_, (I0_) + 4)                                               \
    STEP(CC_[0], RC_[0], (I0_) + 0)                                          \
    STEP(CC_[1], RC_[1], (I0_) + 1)                                          \
    STEP(CC_[2], RC_[2], (I0_) + 2)                                          \
    STEP(CC_[3], RC_[3], (I0_) + 3)                                          \
    if (l == 63 && w < 4) {                                                  \
        __asm__ volatile("s_waitcnt lgkmcnt(0)" ::: "memory");               \
        int pv_ = (I0_) + 3 - 62;                                            \
        if (pv_ > Wmax - 1) pv_ = Wmax - 1;                                  \
        if (pv_ >= 0) prog[w] = pv_;                                         \
    } }

    POLLTO(3)
    LOADG(CA, RA, 0)

    int i0 = 0;
    while (true) {
        PHASE(CA, RA, CB, RB, i0); i0 += 4; if (i0 > imax) break;
        PHASE(CB, RB, CA, RA, i0); i0 += 4; if (i0 > imax) break;
    }

#undef PHASE
#undef STEP
#undef LOADG
#undef POLLTO
#undef CLAMPW

    if (tid == tl - 1) {
        float v = aF * LN2 / (float)(tend + 1);
        if (res) res[b] = v;
        else     atomicAdd(out0, -v / (float)BATCH);
    }
}

// ---------------------------------------------------------------------------
// Fallback DP (r9 version: 2 j/lane, DPP, reads out_lp) for small ws.
// ---------------------------------------------------------------------------
__global__ __launch_bounds__(192, 1) void dp_kernel_fb(
    const float* __restrict__ lp,
    const int* __restrict__ tlen,
    const int* __restrict__ mlen,
    float* __restrict__ res,
    float* __restrict__ out0)
{
    __shared__ float bnd[2][2056];
    __shared__ int   prog[2];

    const int b    = blockIdx.x;
    const int tid  = threadIdx.x;
    const int w    = tid >> 6;
    const int l    = tid & 63;
    const int tend = mlen[b] - 1;
    const int tl   = tlen[b];

    if (tid < 2) prog[tid] = 0;

    int j0c = 2 * tid; if (j0c > 318) j0c = 318;
    const float* r0 = lp + (size_t)(b * TXT + j0c) * MELT;
    const float* r1 = r0 + MELT;

    float A1 = (tid == 0) ? lp[(size_t)b * TXT * MELT] * L2E : -PADM;
    float A2 = -PADM;
    float A1F = A1, A2F = A2;

    if (l == 63 && w < 2) bnd[w][0] = -PADM;
    __syncthreads();

    if (w == 2 && tl < 257) return;

    float ptA2 = -PADM, ptB2 = -PADM;
    const bool is0     = (l == 0);
    const bool isPub   = (l == 63) && (w < 2);
    const bool hasRing = (w > 0);
    int seen = 0;

    const int imax = tend + 63;

    float PA[16], PB[16], PC[16];
    #pragma unroll
    for (int q = 0; q < 8; ++q) { PA[2*q] = r0[1 + q - l]; PA[2*q+1] = r1[1 + q - l]; }
    #pragma unroll
    for (int q = 0; q < 8; ++q) { PB[2*q] = r0[9 + q - l]; PB[2*q+1] = r1[9 + q - l]; }
    #pragma unroll
    for (int q = 0; q < 16; ++q) PA[q] = fmaf(PA[q], L2E, EPSL2);

    const float* p0 = r0 + 17 - l;
    const float* p1 = r1 + 17 - l;

#define RING_RD(BQ_, T0_)                                                    \
    {                                                                        \
        float4 q0_ = *(const float4*)&bnd[w - 1][T0_];                       \
        float4 q1_ = *(const float4*)&bnd[w - 1][(T0_) + 4];                 \
        BQ_[0]=q0_.x; BQ_[1]=q0_.y; BQ_[2]=q0_.z; BQ_[3]=q0_.w;              \
        BQ_[4]=q1_.x; BQ_[5]=q1_.y; BQ_[6]=q1_.z; BQ_[7]=q1_.w;              \
    }
#define RING_POLL(NEED_)                                                     \
    if (seen < (NEED_)) {                                                    \
        int tgt_ = (NEED_) + 32;                                             \
        if (tgt_ > tend - 1) tgt_ = tend - 1;                                \
        if (tgt_ < (NEED_)) tgt_ = (NEED_);                                  \
        volatile int* pv_ = &prog[w - 1];                                    \
        int v_ = *pv_;                                                       \
        while (v_ < tgt_) { __builtin_amdgcn_s_sleep(1); v_ = *pv_; }        \
        seen = v_;                                                           \
        __asm__ volatile("" ::: "memory");                                   \
    }

    float bqC[8];
    if (hasRing) {
        RING_POLL(7)
        RING_RD(bqC, 0)
    } else {
        #pragma unroll
        for (int q = 0; q < 8; ++q) bqC[q] = -PADM;
    }

#define STEP2(Pc_, q_, AQ_)                                                  \
    {                                                                        \
        float pt_ = is0 ? bqC[q_] : ptA2;                                    \
        float m1_ = fmaxf(A1, pt_);                                          \
        float d1_ = A1 - pt_;                                                \
        float e1_ = __builtin_amdgcn_exp2f(-fabsf(d1_));                     \
        float g1_ = __builtin_amdgcn_logf(1.0f + e1_);                       \
        float n1_ = m1_ + g1_ + Pc_[2 * q_];                                 \
        float m2_ = fmaxf(A2, A1);                                           \
        float d2_ = A2 - A1;                                                 \
        float e2_ = __builtin_amdgcn_exp2f(-fabsf(d2_));                     \
        float g2_ = __builtin_amdgcn_logf(1.0f + e2_);                       \
        float n2_ = m2_ + g2_ + Pc_[2 * q_ + 1];                             \
        float ns_ = dpp_shr1(n2_);                                           \
        ptA2 = ptB2; ptB2 = ns_;                                             \
        A1 = n1_; A2 = n2_; AQ_ = n2_;                                       \
    }

#define GROUP2_S(Pc_, Pm_, Pl_, I0_)                                         \
{                                                                            \
    float bqN[8];                                                            \
    if (hasRing) {                                                           \
        const int nt0_ = (I0_) + 7;                                          \
        RING_POLL(nt0_ + 7)                                                  \
        RING_RD(bqN, nt0_)                                                   \
    } else {                                                                 \
        _Pragma("unroll") for (int q_=0;q_<8;++q_) bqN[q_] = -PADM;          \
    }                                                                        \
    _Pragma("unroll") for (int q_=0;q_<8;++q_) {                             \
        Pl_[2*q_] = p0[q_]; Pl_[2*q_+1] = p1[q_];                            \
    }                                                                        \
    float aq2[8];                                                            \
    _Pragma("unroll")                                                        \
    for (int q_=0;q_<8;++q_) STEP2(Pc_, q_, aq2[q_])                         \
    if (isPub) {                                                             \
        const int t63_ = (I0_) - 63;                                         \
        if (t63_ >= 1) {                                                     \
            _Pragma("unroll") for (int q_=0;q_<8;++q_)                       \
                bnd[w][t63_ + q_] = aq2[q_];                                 \
        } else {                                                             \
            _Pragma("unroll") for (int q_=0;q_<8;++q_)                       \
                if (t63_ + q_ >= 1) bnd[w][t63_ + q_] = aq2[q_];             \
        }                                                                    \
        __asm__ volatile("" ::: "memory");                                   \
        int pgv_ = t63_ + 7;                                                 \
        if (pgv_ >= 1) prog[w] = pgv_;                                       \
    }                                                                        \
    p0 += 8; p1 += 8;                                                        \
    _Pragma("unroll") for (int q_=0;q_<16;++q_)                              \
        Pm_[q_] = fmaf(Pm_[q_], L2E, EPSL2);                                 \
    _Pragma("unroll") for (int q_=0;q_<8;++q_) bqC[q_] = bqN[q_];            \
}

#define GROUP2_T(Pc_, Pm_, Pl_, I0_)                                         \
{                                                                            \
    float bqN[8];                                                            \
    if (hasRing) {                                                           \
        const int nt0_ = (I0_) + 7;                                          \
        int need_ = nt0_ + 7; if (need_ > tend - 1) need_ = tend - 1;        \
        RING_POLL(need_)                                                     \
        const int rb_ = nt0_ > 2048 ? 2048 : nt0_;                           \
        RING_RD(bqN, rb_)                                                    \
    } else {                                                                 \
        _Pragma("unroll") for (int q_=0;q_<8;++q_) bqN[q_] = -PADM;          \
    }                                                                        \
    _Pragma("unroll") for (int q_=0;q_<8;++q_) {                             \
        int t_ = (I0_) + 16 + q_ - l;                                        \
        t_ = t_ < 0 ? 0 : (t_ > tend ? tend : t_);                           \
        Pl_[2*q_] = r0[t_]; Pl_[2*q_+1] = r1[t_];                            \
    }                                                                        \
    float aq2[8];                                                            \
    const int vt_ = (I0_) - l;                                               \
    _Pragma("unroll")                                                        \
    for (int q_=0;q_<8;++q_) {                                               \
        STEP2(Pc_, q_, aq2[q_])                                              \
        bool c_ = (vt_ + q_ == tend);                                        \
        A1F = c_ ? A1 : A1F;                                                 \
        A2F = c_ ? A2 : A2F;                                                 \
    }                                                                        \
    if (isPub) {                                                             \
        const int t63_ = (I0_) - 63;                                         \
        _Pragma("unroll") for (int q_=0;q_<8;++q_) {                         \
            int tq_ = t63_ + q_;                                             \
            if (tq_ >= 1 && tq_ <= tend) bnd[w][tq_] = aq2[q_];              \
        }                                                                    \
        __asm__ volatile("" ::: "memory");                                   \
        int pgv_ = t63_ + 7; if (pgv_ > tend) pgv_ = tend;                   \
        if (pgv_ >= 1) prog[w] = pgv_;                                       \
    }                                                                        \
    _Pragma("unroll") for (int q_=0;q_<16;++q_)                              \
        Pm_[q_] = fmaf(Pm_[q_], L2E, EPSL2);                                 \
    _Pragma("unroll") for (int q_=0;q_<8;++q_) bqC[q_] = bqN[q_];            \
}

    int i0 = 1;
    const int sEnd = tend - 23;
    int ph = 0;
    while (i0 <= sEnd) {
        GROUP2_S(PA, PB, PC, i0); i0 += 8;
        if (i0 > sEnd) { ph = 1; break; }
        GROUP2_S(PB, PC, PA, i0); i0 += 8;
        if (i0 > sEnd) { ph = 2; break; }
        GROUP2_S(PC, PA, PB, i0); i0 += 8;
    }
    if (ph == 1) {
        #pragma unroll
        for (int q = 0; q < 16; ++q) {
            float tmp = PA[q]; PA[q] = PB[q]; PB[q] = PC[q]; PC[q] = tmp;
        }
    } else if (ph == 2) {
        #pragma unroll
        for (int q = 0; q < 16; ++q) {
            float tmp = PA[q]; PA[q] = PC[q]; PC[q] = PB[q]; PB[q] = tmp;
        }
    }
    while (i0 <= imax) {
        GROUP2_T(PA, PB, PC, i0); i0 += 8;
        if (i0 > imax) break;
        GROUP2_T(PB, PC, PA, i0); i0 += 8;
        if (i0 > imax) break;
        GROUP2_T(PC, PA, PB, i0); i0 += 8;
    }

#undef GROUP2_S
#undef GROUP2_T
#undef STEP2
#undef RING_RD
#undef RING_POLL

    if (tid == ((tl - 1) >> 1)) {
        float Af = ((tl - 1) & 1) ? A2F : A1F;
        float v = Af * LN2 / (float)(tend + 1);
        if (res) res[b] = v;
        else     atomicAdd(out0, -v / (float)BATCH);
    }
}

__global__ void zero1_kernel(float* out0) { out0[0] = 0.f; }

__global__ void fin_kernel(const float* __restrict__ res, float* __restrict__ out0)
{
    int l = threadIdx.x;
    float v = (l < BATCH) ? res[l] : 0.f;
    #pragma unroll
    for (int off = 32; off; off >>= 1) v += __shfl_down(v, off);
    if (l == 0) out0[0] = -(v / (float)BATCH);
}

// ---------------------------------------------------------------------------
extern "C" void kernel_launch(void* const* d_in, const int* in_sizes, int n_in,
                              void* d_out, int out_size, void* d_ws, size_t ws_size,
                              hipStream_t stream)
{
    const float* mlv = (const float*)d_in[0];
    const float* ms  = (const float*)d_in[1];
    const int*   tl  = (const int*)d_in[2];
    const int*   ml  = (const int*)d_in[3];
    float* out    = (float*)d_out;
    float* out_lp = out + 1;

    const size_t C_bytes = (size_t)BATCH * NW * 5 * 320 * sizeof(float);
    bool res_ok = ws_size >= 64;
    bool has_C  = ws_size >= 64 + C_bytes;
    float* res = res_ok ? (float*)d_ws : nullptr;
    float* Cc  = has_C ? (float*)((char*)d_ws + 64) : nullptr;

    dim3 gA(8, 5, 16);   // t-tiles(256), j-tiles(64), batch
    lp_kernel<<<gA, 256, 0, stream>>>(mlv, ms, out_lp);

    if (!res_ok) zero1_kernel<<<1, 1, 0, stream>>>(out);
    if (has_C) {
        coeff_kernel<<<dim3(32, 16), 320, 0, stream>>>(out_lp, ml, Cc);
        dp_kernel<<<BATCH, 320, 0, stream>>>(Cc, out_lp, tl, ml, res, out);
    } else {
        dp_kernel_fb<<<BATCH, 192, 0, stream>>>(out_lp, tl, ml, res, out);
    }
    if (res_ok) fin_kernel<<<1, 64, 0, stream>>>(res, out);
}

// Round 11
// 258.408 us; speedup vs baseline: 3.6291x; 3.6291x over previous
//
#include <hip/hip_runtime.h>

#define BATCH 16
#define TXT   320
#define NMELC 80
#define MELT  2000
#define DIAGS 2240   // rows of skewed lpS (max written 2206; dp reads < 2214)
#define PADM  1.0e12f
#define EPSC  1e-7f
#define L2E   1.4426950408889634f
#define LN2   0.6931471805599453f
#define EPSL2 1.4426950e-7f

// ---------------------------------------------------------------------------
// Kernel A: log_prob[b,j,t] = s*(xx - 2xm + mm),  s = -0.5/80  (r9 structure)
// ---------------------------------------------------------------------------
__global__ __launch_bounds__(256) void lp_kernel(
    const float* __restrict__ mlv,   // (B,320,160)
    const float* __restrict__ ms,    // (B,80,2000)
    float* __restrict__ out_lp)      // (B,320,2000)  (d_out+1)
{
    __shared__ float Gt[16][64];
    __shared__ float Ft[16][256];
    __shared__ float bias_s[64];
    __shared__ float bias_p[256];

    const int b   = blockIdx.z;
    const int j0  = blockIdx.y * 64;
    const int t0  = blockIdx.x * 256;
    const int tid = threadIdx.x;
    const float s = -0.00625f;  // -0.5/80

    const float* mlv_b = mlv + (size_t)b * TXT * 160;
    const float* ms_b  = ms  + (size_t)b * NMELC * MELT;

    {
        const int jj = tid >> 2;
        const int q  = tid & 3;
        const float* p = mlv_b + (size_t)(j0 + jj) * 160 + q * 20;
        float part = 0.f;
        #pragma unroll
        for (int c = 0; c < 20; ++c) {
            float mu = p[c];
            float lv = p[c + 80];
            float iv = __expf(-lv);
            part += mu * mu * iv + lv;
        }
        bias_p[tid] = part;
    }
    __syncthreads();
    if (tid < 64) {
        float v = bias_p[tid * 4] + bias_p[tid * 4 + 1] +
                  bias_p[tid * 4 + 2] + bias_p[tid * 4 + 3];
        bias_s[tid] = s * v;
    }

    float acc[8][8];
    #pragma unroll
    for (int i = 0; i < 8; ++i)
        #pragma unroll
        for (int k = 0; k < 8; ++k) acc[i][k] = 0.f;

    const int jg = tid >> 5;   // 0..7
    const int tg = tid & 31;   // 0..31

    for (int kc = 0; kc < 10; ++kc) {
        const int c0 = kc * 8;
        __syncthreads();
        #pragma unroll
        for (int i = 0; i < 2; ++i) {
            int f   = tid + i * 256;
            int cr  = f >> 6;
            int col = f & 63;
            float mu = mlv_b[(size_t)(j0 + col) * 160 + (c0 + cr)];
            float lv = mlv_b[(size_t)(j0 + col) * 160 + (80 + c0 + cr)];
            float iv = __expf(-lv);
            Gt[cr][col]     = s * iv;
            Gt[cr + 8][col] = -2.f * s * mu * iv;
        }
        #pragma unroll
        for (int i = 0; i < 2; ++i) {
            int f   = tid + i * 256;
            int row = f >> 6;
            int c4  = f & 63;
            int t   = t0 + c4 * 4;
            float4 v = (t + 3 < MELT)
                ? *(const float4*)&ms_b[(size_t)(c0 + row) * MELT + t]
                : make_float4(0.f, 0.f, 0.f, 0.f);
            *(float4*)&Ft[row][c4 * 4] =
                make_float4(v.x * v.x, v.y * v.y, v.z * v.z, v.w * v.w);
            *(float4*)&Ft[row + 8][c4 * 4] = v;
        }
        __syncthreads();
        #pragma unroll
        for (int k = 0; k < 16; ++k) {
            float4 g0 = *(const float4*)&Gt[k][jg * 8];
            float4 g1 = *(const float4*)&Gt[k][jg * 8 + 4];
            float4 f0 = *(const float4*)&Ft[k][tg * 8];
            float4 f1 = *(const float4*)&Ft[k][tg * 8 + 4];
            float ga[8] = {g0.x, g0.y, g0.z, g0.w, g1.x, g1.y, g1.z, g1.w};
            float fa[8] = {f0.x, f0.y, f0.z, f0.w, f1.x, f1.y, f1.z, f1.w};
            #pragma unroll
            for (int ji = 0; ji < 8; ++ji)
                #pragma unroll
                for (int ti = 0; ti < 8; ++ti)
                    acc[ji][ti] = fmaf(ga[ji], fa[ti], acc[ji][ti]);
        }
    }

    #pragma unroll
    for (int ji = 0; ji < 8; ++ji) {
        int j = j0 + jg * 8 + ji;
        float bs = bias_s[jg * 8 + ji];
        float* orow = out_lp + (size_t)(b * TXT + j) * MELT;
        #pragma unroll
        for (int ti = 0; ti < 8; ++ti) {
            int t = t0 + tg * 8 + ti;
            if (t < MELT) orow[t] = acc[ji][ti] + bs;
        }
    }
}

// ---------------------------------------------------------------------------
// Kernel A2: LDS-transpose into pair-skewed layout.
// lpS[b][t + (j>>1)][j] = lp*L2E + EPS*L2E.
// 64j x 64t tile staged in T[64][65] (reads 2-way bank aliased = free),
// writes are 64-consecutive-float coalesced rows.
// ---------------------------------------------------------------------------
__global__ __launch_bounds__(256) void tr_kernel(
    const float* __restrict__ lp,    // (B,320,2000)
    float* __restrict__ lpS)         // (B,DIAGS,320)
{
    __shared__ float T[64][65];
    const int b    = blockIdx.z;
    const int j0   = blockIdx.y * 64;
    const int t0   = blockIdx.x * 64;
    const int tid  = threadIdx.x;
    const int lane = tid & 63;
    const int qg   = tid >> 6;       // 0..3

    // stage: each wave reads one j-row of 64 t (coalesced), 16 rows/quarter
    #pragma unroll 4
    for (int it = 0; it < 16; ++it) {
        int j = j0 + qg * 16 + it;
        int t = t0 + lane;
        float v = (t < MELT) ? lp[((size_t)b * TXT + j) * MELT + t] : 0.f;
        T[qg * 16 + it][lane] = fmaf(v, L2E, EPSL2);
    }
    __syncthreads();

    // write: output row r = t + (j>>1); r in [rbase, rbase+94]
    const int rbase = t0 + (j0 >> 1);
    float* orow = lpS + ((size_t)b * DIAGS + rbase) * TXT + j0 + lane;
    #pragma unroll 4
    for (int k = 0; k < 24; ++k) {
        int d = qg + 4 * k;          // r - rbase
        if (d > 94) break;
        int tloc = d - (lane >> 1);
        if (tloc >= 0 && tloc < 64 && (t0 + tloc) < MELT)
            orow[(size_t)d * TXT] = T[lane][tloc];
    }
}

// ---------------------------------------------------------------------------
// Kernel B: forward DP v10 — 2 j/lane (j=2tid,2tid+1), systolic skew i=t+l.
// COALESCED float2 loads from pair-skewed pre-scaled lpS (row i+64w, no
// rescale in loop) + DPP wave_shr:1 neighbor exchange (no LDS on the chain).
// Both round-4..9 bottlenecks (TA divergence + ds_bpermute) removed at once.
// 3 waves, 2 LDS rings w/ slack poll.
// ---------------------------------------------------------------------------
__device__ __forceinline__ float dpp_shr1(float x) {
    return __int_as_float(__builtin_amdgcn_update_dpp(
        0, __float_as_int(x), 0x138 /*wave_shr:1*/, 0xF, 0xF, false));
}

__global__ __launch_bounds__(192, 1) void dp_kernel(
    const float* __restrict__ lpS,   // (B,DIAGS,320) pre-scaled log2 domain
    const int* __restrict__ tlen,
    const int* __restrict__ mlen,
    float* __restrict__ res,
    float* __restrict__ out0)
{
    __shared__ float bnd[2][2056];
    __shared__ int   prog[2];

    const int b    = blockIdx.x;
    const int tid  = threadIdx.x;
    const int w    = tid >> 6;
    const int l    = tid & 63;
    const int tend = mlen[b] - 1;
    const int tl   = tlen[b];

    if (tid < 2) prog[tid] = 0;

    // lane reads lpS row (i + 64w), cols (2*tid, 2*tid+1)
    const float* rowp = lpS + (size_t)b * DIAGS * TXT
                      + (size_t)(64 * w) * TXT + 2 * tid;

    float A1 = (tid == 0) ? rowp[0] - EPSL2 : -PADM;   // alpha_0[0] = lp00*L2E
    float A2 = -PADM;
    float A1F = A1, A2F = A2;

    if (l == 63 && w < 2) bnd[w][0] = -PADM;
    __syncthreads();

    if (w == 2 && tl < 257) return;   // wave 2 unused

    float ptA2 = -PADM, ptB2 = -PADM;   // neighbor odd-j alpha, 2-deep pipe
    const bool is0     = (l == 0);
    const bool isPub   = (l == 63) && (w < 2);
    const bool hasRing = (w > 0);
    int seen = 0;

    const int imax = tend + 63;

    // 3-deep rotating prefetch, one float2 row-load per iteration slot
    float PA[16], PB[16], PC[16];
    #pragma unroll
    for (int q = 0; q < 8; ++q) {
        float2 v = *(const float2*)&rowp[(size_t)(1 + q) * TXT];
        PA[2 * q] = v.x; PA[2 * q + 1] = v.y;
    }
    #pragma unroll
    for (int q = 0; q < 8; ++q) {
        float2 v = *(const float2*)&rowp[(size_t)(9 + q) * TXT];
        PB[2 * q] = v.x; PB[2 * q + 1] = v.y;
    }
    const float* pref = rowp + (size_t)17 * TXT;

#define RING_RD(BQ_, T0_)                                                    \
    {                                                                        \
        float4 r0_ = *(const float4*)&bnd[w - 1][T0_];                       \
        float4 r1_ = *(const float4*)&bnd[w - 1][(T0_) + 4];                 \
        BQ_[0]=r0_.x; BQ_[1]=r0_.y; BQ_[2]=r0_.z; BQ_[3]=r0_.w;              \
        BQ_[4]=r1_.x; BQ_[5]=r1_.y; BQ_[6]=r1_.z; BQ_[7]=r1_.w;              \
    }
#define RING_POLL(NEED_)                                                     \
    if (seen < (NEED_)) {                                                    \
        int tgt_ = (NEED_) + 32;                                             \
        if (tgt_ > tend - 1) tgt_ = tend - 1;                                \
        if (tgt_ < (NEED_)) tgt_ = (NEED_);                                  \
        volatile int* pv_ = &prog[w - 1];                                    \
        int v_ = *pv_;                                                       \
        while (v_ < tgt_) { __builtin_amdgcn_s_sleep(1); v_ = *pv_; }        \
        seen = v_;                                                           \
        __asm__ volatile("" ::: "memory");                                   \
    }

    float bqC[8];
    if (hasRing) {
        RING_POLL(7)
        RING_RD(bqC, 0)
    } else {
        #pragma unroll
        for (int q = 0; q < 8; ++q) bqC[q] = -PADM;
    }

// one iteration = 2 DP j-steps; both lse's parallel; DPP on the exchange
#define STEP2(Pc_, q_, AQ_)                                                  \
    {                                                                        \
        float pt_ = is0 ? bqC[q_] : ptA2;                                    \
        float m1_ = fmaxf(A1, pt_);                                          \
        float d1_ = A1 - pt_;                                                \
        float e1_ = __builtin_amdgcn_exp2f(-fabsf(d1_));                     \
        float g1_ = __builtin_amdgcn_logf(1.0f + e1_);                       \
        float n1_ = m1_ + g1_ + Pc_[2 * q_];                                 \
        float m2_ = fmaxf(A2, A1);                                           \
        float d2_ = A2 - A1;                                                 \
        float e2_ = __builtin_amdgcn_exp2f(-fabsf(d2_));                     \
        float g2_ = __builtin_amdgcn_logf(1.0f + e2_);                       \
        float n2_ = m2_ + g2_ + Pc_[2 * q_ + 1];                             \
        float ns_ = dpp_shr1(n2_);                                           \
        ptA2 = ptB2; ptB2 = ns_;                                             \
        A1 = n1_; A2 = n2_; AQ_ = n2_;                                       \
    }

#define GROUP2_S(Pc_, Pl_, I0_)                                              \
{                                                                            \
    float bqN[8];                                                            \
    if (hasRing) {                                                           \
        const int nt0_ = (I0_) + 7;                                          \
        RING_POLL(nt0_ + 7)                                                  \
        RING_RD(bqN, nt0_)                                                   \
    } else {                                                                 \
        _Pragma("unroll") for (int q_=0;q_<8;++q_) bqN[q_] = -PADM;          \
    }                                                                        \
    _Pragma("unroll") for (int q_=0;q_<8;++q_) {                             \
        float2 v_ = *(const float2*)&pref[(size_t)q_ * TXT];                 \
        Pl_[2*q_] = v_.x; Pl_[2*q_+1] = v_.y;                                \
    }                                                                        \
    float aq2[8];                                                            \
    _Pragma("unroll")                                                        \
    for (int q_=0;q_<8;++q_) STEP2(Pc_, q_, aq2[q_])                         \
    if (isPub) {                                                             \
        const int t63_ = (I0_) - 63;                                         \
        if (t63_ >= 1) {                                                     \
            _Pragma("unroll") for (int q_=0;q_<8;++q_)                       \
                bnd[w][t63_ + q_] = aq2[q_];                                 \
        } else {                                                             \
            _Pragma("unroll") for (int q_=0;q_<8;++q_)                       \
                if (t63_ + q_ >= 1) bnd[w][t63_ + q_] = aq2[q_];             \
        }                                                                    \
        __asm__ volatile("" ::: "memory");  /* DS pipe is in-order */        \
        int pgv_ = t63_ + 7;                                                 \
        if (pgv_ >= 1) prog[w] = pgv_;                                       \
    }                                                                        \
    pref += (size_t)8 * TXT;                                                 \
    _Pragma("unroll") for (int q_=0;q_<8;++q_) bqC[q_] = bqN[q_];            \
}

#define GROUP2_T(Pc_, Pl_, I0_)                                              \
{                                                                            \
    float bqN[8];                                                            \
    if (hasRing) {                                                           \
        const int nt0_ = (I0_) + 7;                                          \
        int need_ = nt0_ + 7; if (need_ > tend - 1) need_ = tend - 1;        \
        RING_POLL(need_)                                                     \
        const int rb_ = nt0_ > 2048 ? 2048 : nt0_;                           \
        RING_RD(bqN, rb_)                                                    \
    } else {                                                                 \
        _Pragma("unroll") for (int q_=0;q_<8;++q_) bqN[q_] = -PADM;          \
    }                                                                        \
    _Pragma("unroll") for (int q_=0;q_<8;++q_) {                             \
        float2 v_ = *(const float2*)&pref[(size_t)q_ * TXT];                 \
        Pl_[2*q_] = v_.x; Pl_[2*q_+1] = v_.y;                                \
    }                                                                        \
    float aq2[8];                                                            \
    const int vt_ = (I0_) - l;                                               \
    _Pragma("unroll")                                                        \
    for (int q_=0;q_<8;++q_) {                                               \
        STEP2(Pc_, q_, aq2[q_])                                              \
        bool c_ = (vt_ + q_ == tend);                                        \
        A1F = c_ ? A1 : A1F;                                                 \
        A2F = c_ ? A2 : A2F;                                                 \
    }                                                                        \
    if (isPub) {                                                             \
        const int t63_ = (I0_) - 63;                                         \
        _Pragma("unroll") for (int q_=0;q_<8;++q_) {                         \
            int tq_ = t63_ + q_;                                             \
            if (tq_ >= 1 && tq_ <= tend) bnd[w][tq_] = aq2[q_];              \
        }                                                                    \
        __asm__ volatile("" ::: "memory");                                   \
        int pgv_ = t63_ + 7; if (pgv_ > tend) pgv_ = tend;                   \
        if (pgv_ >= 1) prog[w] = pgv_;                                       \
    }                                                                        \
    pref += (size_t)8 * TXT;                                                 \
    _Pragma("unroll") for (int q_=0;q_<8;++q_) bqC[q_] = bqN[q_];            \
}

    int i0 = 1;
    const int sEnd = tend - 23;   // steady: latch can't fire
    int ph = 0;
    while (i0 <= sEnd) {
        GROUP2_S(PA, PC, i0); i0 += 8;
        if (i0 > sEnd) { ph = 1; break; }
        GROUP2_S(PB, PA, i0); i0 += 8;
        if (i0 > sEnd) { ph = 2; break; }
        GROUP2_S(PC, PB, i0); i0 += 8;
    }
    if (ph == 1) {
        #pragma unroll
        for (int q = 0; q < 16; ++q) {
            float tmp = PA[q]; PA[q] = PB[q]; PB[q] = PC[q]; PC[q] = tmp;
        }
    } else if (ph == 2) {
        #pragma unroll
        for (int q = 0; q < 16; ++q) {
            float tmp = PA[q]; PA[q] = PC[q]; PC[q] = PB[q]; PB[q] = tmp;
        }
    }
    while (i0 <= imax) {
        GROUP2_T(PA, PC, i0); i0 += 8;
        if (i0 > imax) break;
        GROUP2_T(PB, PA, i0); i0 += 8;
        if (i0 > imax) break;
        GROUP2_T(PC, PB, i0); i0 += 8;
    }

#undef GROUP2_S
#undef GROUP2_T
#undef STEP2
#undef RING_RD
#undef RING_POLL

    if (tid == ((tl - 1) >> 1)) {
        float Af = ((tl - 1) & 1) ? A2F : A1F;
        float v = Af * LN2 / (float)(tend + 1);
        if (res) res[b] = v;
        else     atomicAdd(out0, -v / (float)BATCH);
    }
}

// ---------------------------------------------------------------------------
// Fallback DP (r9: 2 j/lane, DPP, reads out_lp directly) for small ws.
// ---------------------------------------------------------------------------
__global__ __launch_bounds__(192, 1) void dp_kernel_fb(
    const float* __restrict__ lp,
    const int* __restrict__ tlen,
    const int* __restrict__ mlen,
    float* __restrict__ res,
    float* __restrict__ out0)
{
    __shared__ float bnd[2][2056];
    __shared__ int   prog[2];

    const int b    = blockIdx.x;
    const int tid  = threadIdx.x;
    const int w    = tid >> 6;
    const int l    = tid & 63;
    const int tend = mlen[b] - 1;
    const int tl   = tlen[b];

    if (tid < 2) prog[tid] = 0;

    int j0c = 2 * tid; if (j0c > 318) j0c = 318;
    const float* r0 = lp + (size_t)(b * TXT + j0c) * MELT;
    const float* r1 = r0 + MELT;

    float A1 = (tid == 0) ? lp[(size_t)b * TXT * MELT] * L2E : -PADM;
    float A2 = -PADM;
    float A1F = A1, A2F = A2;

    if (l == 63 && w < 2) bnd[w][0] = -PADM;
    __syncthreads();

    if (w == 2 && tl < 257) return;

    float ptA2 = -PADM, ptB2 = -PADM;
    const bool is0     = (l == 0);
    const bool isPub   = (l == 63) && (w < 2);
    const bool hasRing = (w > 0);
    int seen = 0;

    const int imax = tend + 63;

    float PA[16], PB[16], PC[16];
    #pragma unroll
    for (int q = 0; q < 8; ++q) { PA[2*q] = r0[1 + q - l]; PA[2*q+1] = r1[1 + q - l]; }
    #pragma unroll
    for (int q = 0; q < 8; ++q) { PB[2*q] = r0[9 + q - l]; PB[2*q+1] = r1[9 + q - l]; }
    #pragma unroll
    for (int q = 0; q < 16; ++q) PA[q] = fmaf(PA[q], L2E, EPSL2);

    const float* p0 = r0 + 17 - l;
    const float* p1 = r1 + 17 - l;

#define RING_RD(BQ_, T0_)                                                    \
    {                                                                        \
        float4 q0_ = *(const float4*)&bnd[w - 1][T0_];                       \
        float4 q1_ = *(const float4*)&bnd[w - 1][(T0_) + 4];                 \
        BQ_[0]=q0_.x; BQ_[1]=q0_.y; BQ_[2]=q0_.z; BQ_[3]=q0_.w;              \
        BQ_[4]=q1_.x; BQ_[5]=q1_.y; BQ_[6]=q1_.z; BQ_[7]=q1_.w;              \
    }
#define RING_POLL(NEED_)                                                     \
    if (seen < (NEED_)) {                                                    \
        int tgt_ = (NEED_) + 32;                                             \
        if (tgt_ > tend - 1) tgt_ = tend - 1;                                \
        if (tgt_ < (NEED_)) tgt_ = (NEED_);                                  \
        volatile int* pv_ = &prog[w - 1];                                    \
        int v_ = *pv_;                                                       \
        while (v_ < tgt_) { __builtin_amdgcn_s_sleep(1); v_ = *pv_; }        \
        seen = v_;                                                           \
        __asm__ volatile("" ::: "memory");                                   \
    }

    float bqC[8];
    if (hasRing) {
        RING_POLL(7)
        RING_RD(bqC, 0)
    } else {
        #pragma unroll
        for (int q = 0; q < 8; ++q) bqC[q] = -PADM;
    }

#define STEP2(Pc_, q_, AQ_)                                                  \
    {                                                                        \
        float pt_ = is0 ? bqC[q_] : ptA2;                                    \
        float m1_ = fmaxf(A1, pt_);                                          \
        float d1_ = A1 - pt_;                                                \
        float e1_ = __builtin_amdgcn_exp2f(-fabsf(d1_));                     \
        float g1_ = __builtin_amdgcn_logf(1.0f + e1_);                       \
        float n1_ = m1_ + g1_ + Pc_[2 * q_];                                 \
        float m2_ = fmaxf(A2, A1);                                           \
        float d2_ = A2 - A1;                                                 \
        float e2_ = __builtin_amdgcn_exp2f(-fabsf(d2_));                     \
        float g2_ = __builtin_amdgcn_logf(1.0f + e2_);                       \
        float n2_ = m2_ + g2_ + Pc_[2 * q_ + 1];                             \
        float ns_ = __int_as_float(__builtin_amdgcn_update_dpp(              \
            0, __float_as_int(n2_), 0x138, 0xF, 0xF, false));                \
        ptA2 = ptB2; ptB2 = ns_;                                             \
        A1 = n1_; A2 = n2_; AQ_ = n2_;                                       \
    }

#define GROUP2_S(Pc_, Pm_, Pl_, I0_)                                         \
{                                                                            \
    float bqN[8];                                                            \
    if (hasRing) {                                                           \
        const int nt0_ = (I0_) + 7;                                          \
        RING_POLL(nt0_ + 7)                                                  \
        RING_RD(bqN, nt0_)                                                   \
    } else {                                                                 \
        _Pragma("unroll") for (int q_=0;q_<8;++q_) bqN[q_] = -PADM;          \
    }                                                                        \
    _Pragma("unroll") for (int q_=0;q_<8;++q_) {                             \
        Pl_[2*q_] = p0[q_]; Pl_[2*q_+1] = p1[q_];                            \
    }                                                                        \
    float aq2[8];                                                            \
    _Pragma("unroll")                                                        \
    for (int q_=0;q_<8;++q_) STEP2(Pc_, q_, aq2[q_])                         \
    if (isPub) {                                                             \
        const int t63_ = (I0_) - 63;                                         \
        if (t63_ >= 1) {                                                     \
            _Pragma("unroll") for (int q_=0;q_<8;++q_)                       \
                bnd[w][t63_ + q_] = aq2[q_];                                 \
        } else {                                                             \
            _Pragma("unroll") for (int q_=0;q_<8;++q_)                       \
                if (t63_ + q_ >= 1) bnd[w][t63_ + q_] = aq2[q_];             \
        }                                                                    \
        __asm__ volatile("" ::: "memory");                                   \
        int pgv_ = t63_ + 7;                                                 \
        if (pgv_ >= 1) prog[w] = pgv_;                                       \
    }                                                                        \
    p0 += 8; p1 += 8;                                                        \
    _Pragma("unroll") for (int q_=0;q_<16;++q_)                              \
        Pm_[q_] = fmaf(Pm_[q_], L2E, EPSL2);                                 \
    _Pragma("unroll") for (int q_=0;q_<8;++q_) bqC[q_] = bqN[q_];            \
}

#define GROUP2_T(Pc_, Pm_, Pl_, I0_)                                         \
{                                                                            \
    float bqN[8];                                                            \
    if (hasRing) {                                                           \
        const int nt0_ = (I0_) + 7;                                          \
        int need_ = nt0_ + 7; if (need_ > tend - 1) need_ = tend - 1;        \
        RING_POLL(need_)                                                     \
        const int rb_ = nt0_ > 2048 ? 2048 : nt0_;                           \
        RING_RD(bqN, rb_)                                                    \
    } else {                                                                 \
        _Pragma("unroll") for (int q_=0;q_<8;++q_) bqN[q_] = -PADM;          \
    }                                                                        \
    _Pragma("unroll") for (int q_=0;q_<8;++q_) {                             \
        int t_ = (I0_) + 16 + q_ - l;                                        \
        t_ = t_ < 0 ? 0 : (t_ > tend ? tend : t_);                           \
        Pl_[2*q_] = r0[t_]; Pl_[2*q_+1] = r1[t_];                            \
    }                                                                        \
    float aq2[8];                                                            \
    const int vt_ = (I0_) - l;                                               \
    _Pragma("unroll")                                                        \
    for (int q_=0;q_<8;++q_) {                                               \
        STEP2(Pc_, q_, aq2[q_])                                              \
        bool c_ = (vt_ + q_ == tend);                                        \
        A1F = c_ ? A1 : A1F;                                                 \
        A2F = c_ ? A2 : A2F;                                                 \
    }                                                                        \
    if (isPub) {                                                             \
        const int t63_ = (I0_) - 63;                                         \
        _Pragma("unroll") for (int q_=0;q_<8;++q_) {                         \
            int tq_ = t63_ + q_;                                             \
            if (tq_ >= 1 && tq_ <= tend) bnd[w][tq_] = aq2[q_];              \
        }                                                                    \
        __asm__ volatile("" ::: "memory");                                   \
        int pgv_ = t63_ + 7; if (pgv_ > tend) pgv_ = tend;                   \
        if (pgv_ >= 1) prog[w] = pgv_;                                       \
    }                                                                        \
    _Pragma("unroll") for (int q_=0;q_<16;++q_)                              \
        Pm_[q_] = fmaf(Pm_[q_], L2E, EPSL2);                                 \
    _Pragma("unroll") for (int q_=0;q_<8;++q_) bqC[q_] = bqN[q_];            \
}

    int i0 = 1;
    const int sEnd = tend - 23;
    int ph = 0;
    while (i0 <= sEnd) {
        GROUP2_S(PA, PB, PC, i0); i0 += 8;
        if (i0 > sEnd) { ph = 1; break; }
        GROUP2_S(PB, PC, PA, i0); i0 += 8;
        if (i0 > sEnd) { ph = 2; break; }
        GROUP2_S(PC, PA, PB, i0); i0 += 8;
    }
    if (ph == 1) {
        #pragma unroll
        for (int q = 0; q < 16; ++q) {
            float tmp = PA[q]; PA[q] = PB[q]; PB[q] = PC[q]; PC[q] = tmp;
        }
    } else if (ph == 2) {
        #pragma unroll
        for (int q = 0; q < 16; ++q) {
            float tmp = PA[q]; PA[q] = PC[q]; PC[q] = PB[q]; PB[q] = tmp;
        }
    }
    while (i0 <= imax) {
        GROUP2_T(PA, PB, PC, i0); i0 += 8;
        if (i0 > imax) break;
        GROUP2_T(PB, PC, PA, i0); i0 += 8;
        if (i0 > imax) break;
        GROUP2_T(PC, PA, PB, i0); i0 += 8;
    }

#undef GROUP2_S
#undef GROUP2_T
#undef STEP2
#undef RING_RD
#undef RING_POLL

    if (tid == ((tl - 1) >> 1)) {
        float Af = ((tl - 1) & 1) ? A2F : A1F;
        float v = Af * LN2 / (float)(tend + 1);
        if (res) res[b] = v;
        else     atomicAdd(out0, -v / (float)BATCH);
    }
}

__global__ void zero1_kernel(float* out0) { out0[0] = 0.f; }

__global__ void fin_kernel(const float* __restrict__ res, float* __restrict__ out0)
{
    int l = threadIdx.x;
    float v = (l < BATCH) ? res[l] : 0.f;
    #pragma unroll
    for (int off = 32; off; off >>= 1) v += __shfl_down(v, off);
    if (l == 0) out0[0] = -(v / (float)BATCH);
}

// ---------------------------------------------------------------------------
extern "C" void kernel_launch(void* const* d_in, const int* in_sizes, int n_in,
                              void* d_out, int out_size, void* d_ws, size_t ws_size,
                              hipStream_t stream)
{
    const float* mlv = (const float*)d_in[0];
    const float* ms  = (const float*)d_in[1];
    const int*   tl  = (const int*)d_in[2];
    const int*   ml  = (const int*)d_in[3];
    float* out    = (float*)d_out;
    float* out_lp = out + 1;

    const size_t lpS_bytes = (size_t)BATCH * DIAGS * TXT * sizeof(float);
    bool res_ok = ws_size >= 128;
    bool has_S  = ws_size >= 128 + lpS_bytes;
    float* res = res_ok ? (float*)d_ws : nullptr;
    float* lpS = has_S ? (float*)((char*)d_ws + 128) : nullptr;

    dim3 gA(8, 5, 16);   // t-tiles(256), j-tiles(64), batch
    lp_kernel<<<gA, 256, 0, stream>>>(mlv, ms, out_lp);

    if (!res_ok) zero1_kernel<<<1, 1, 0, stream>>>(out);
    if (has_S) {
        tr_kernel<<<dim3(32, 5, 16), 256, 0, stream>>>(out_lp, lpS);
        dp_kernel<<<BATCH, 192, 0, stream>>>(lpS, tl, ml, res, out);
    } else {
        dp_kernel_fb<<<BATCH, 192, 0, stream>>>(out_lp, tl, ml, res, out);
    }
    if (res_ok) fin_kernel<<<1, 64, 0, stream>>>(res, out);
}